// Round 4
// baseline (898.090 us; speedup 1.0000x reference)
//
#include <hip/hip_runtime.h>

#define S_LEN 1024
#define BATCH 4096
#define NIN 64
#define NHID 128
#define BT 16      // batch rows per block

typedef __attribute__((ext_vector_type(8))) short bf16x8;
typedef __attribute__((ext_vector_type(4))) float f32x4;

__device__ __forceinline__ unsigned short f2bf(float f) {
    union { float f; unsigned u; } v; v.f = f;
    unsigned r = v.u + 0x7FFFu + ((v.u >> 16) & 1u);   // RNE
    return (unsigned short)(r >> 16);
}
__device__ __forceinline__ float bf2f(unsigned short h) {
    union { float f; unsigned u; } v; v.u = ((unsigned)h) << 16;
    return v.f;
}
__device__ __forceinline__ unsigned cvt_pk(float lo, float hi) {
    unsigned r;
    asm("v_cvt_pk_bf16_f32 %0, %1, %2" : "=v"(r) : "v"(lo), "v"(hi));
    return r;
}
__device__ __forceinline__ float tanh_fast(float z) {
    float u = __builtin_amdgcn_exp2f(z * 2.885390081777927f);
    return (u - 1.0f) * __builtin_amdgcn_rcpf(u + 1.0f);
}
// Barrier WITHOUT vmcnt(0) drain (global x-prefetch stays in flight)
__device__ __forceinline__ void lds_barrier() {
    asm volatile("s_waitcnt lgkmcnt(0)\n\ts_barrier" ::: "memory");
}

__global__ __launch_bounds__(512, 2)
void rnn_kernel(const float* __restrict__ x,
                const float* __restrict__ W_ih,
                const float* __restrict__ b_ih,
                const float* __restrict__ W_hh,
                const float* __restrict__ b_hh,
                float* __restrict__ out)
{
    // h layout: [buf][kk][lane][8 bf16] — lane-contiguous 16B chunks per k-tile.
    // Read: lane l -> b128 @ buf*4096 + kk*1024 + l*16  (conflict-free, m97 pattern)
    __shared__ __align__(16) char hbuf[2 * 4096];

    const int tid  = threadIdx.x;
    const int w    = tid >> 6;    // wave: hidden rows [16w, 16w+16)
    const int lane = tid & 63;
    const int col  = lane & 15;   // batch index within tile
    const int kg   = lane >> 4;   // k-group 0..3

    const int bb0 = blockIdx.x * BT;

    // zero both h buffers (h_0 = 0)
    for (int i = tid; i < 2048; i += 512) ((int*)hbuf)[i] = 0;

    const int rd_off = lane * 16;
    // write dest for this lane's 4 h values (k = 16w+4kg .. +3), derived mapping:
    const int wr_off = ((w >> 1) << 10) + ((2 * (w & 1) + (kg >> 1)) << 8)
                     + (col << 4) + ((kg & 1) << 3);

    // ---- persistent weight fragments. W_hh = hi+lo bf16 split; W_ih hi only.
    const int nrow = 16 * w + col;
    bf16x8 wih_h[2], whh_h[4], whh_l[4];
    #pragma unroll
    for (int kk = 0; kk < 2; ++kk) {
        const float* p = W_ih + nrow * NIN + kk * 32 + kg * 8;
        #pragma unroll
        for (int j = 0; j < 8; ++j) wih_h[kk][j] = (short)f2bf(p[j]);
    }
    #pragma unroll
    for (int kk = 0; kk < 4; ++kk) {
        const float* p = W_hh + nrow * NHID + kk * 32 + kg * 8;
        #pragma unroll
        for (int j = 0; j < 8; ++j) {
            float f = p[j];
            unsigned short hi = f2bf(f);
            whh_h[kk][j] = (short)hi;
            whh_l[kk][j] = (short)f2bf(f - bf2f(hi));
        }
    }

    f32x4 biasv;
    {
        f32x4 bi = *(const f32x4*)(b_ih + 16 * w + 4 * kg);
        f32x4 bh = *(const f32x4*)(b_hh + 16 * w + 4 * kg);
        biasv = bi + bh;
    }

    const float* xlane = x + ((size_t)bb0 + col) * NIN + kg * 8;

    auto loadStage = [&](f32x4& v0, f32x4& v1, f32x4& v2, f32x4& v3, int t) {
        if (t < S_LEN) {
            const float* p = xlane + (size_t)t * (BATCH * NIN);
            v0 = *(const f32x4*)(p);      v1 = *(const f32x4*)(p + 4);
            v2 = *(const f32x4*)(p + 32); v3 = *(const f32x4*)(p + 36);
        }
    };
    auto packP = [&](bf16x8& Pa, bf16x8& Pb, const f32x4& v0, const f32x4& v1,
                     const f32x4& v2, const f32x4& v3) {
        union { bf16x8 v; unsigned u[4]; } a, b;
        a.u[0] = cvt_pk(v0[0], v0[1]); a.u[1] = cvt_pk(v0[2], v0[3]);
        a.u[2] = cvt_pk(v1[0], v1[1]); a.u[3] = cvt_pk(v1[2], v1[3]);
        b.u[0] = cvt_pk(v2[0], v2[1]); b.u[1] = cvt_pk(v2[2], v2[3]);
        b.u[2] = cvt_pk(v3[0], v3[1]); b.u[3] = cvt_pk(v3[2], v3[3]);
        Pa = a.v; Pb = b.v;
    };

    char* lbase = hbuf;

    // Step t: consume packed P (= x(t+1)) -> xp(t+1); repack P <- raw R (= x(t+3));
    // refill R <- x(t+5). h chain: ds_read -> 4x depth-2 MFMA -> tanh -> ds_write.
    auto step = [&](int t, f32x4& r0, f32x4& r1, f32x4& r2, f32x4& r3,
                    bf16x8& Pa, bf16x8& Pb, const f32x4& xp_cur, f32x4& xp_next) {
        char* rbase = lbase + ((t & 1) << 12) + rd_off;
        bf16x8 hf0 = *(const bf16x8*)(rbase);
        bf16x8 hf1 = *(const bf16x8*)(rbase + 1024);
        bf16x8 hf2 = *(const bf16x8*)(rbase + 2048);
        bf16x8 hf3 = *(const bf16x8*)(rbase + 3072);

        if (t + 1 < S_LEN) {
            f32x4 xp = biasv;
            xp = __builtin_amdgcn_mfma_f32_16x16x32_bf16(wih_h[0], Pa, xp, 0, 0, 0);
            xp = __builtin_amdgcn_mfma_f32_16x16x32_bf16(wih_h[1], Pb, xp, 0, 0, 0);
            xp_next = xp;
        }
        packP(Pa, Pb, r0, r1, r2, r3);     // x(t+3): loaded 2 steps ago, no stall
        loadStage(r0, r1, r2, r3, t + 5);  // issue, consumed (cvt) at t+2

        f32x4 z4 = {0.f, 0.f, 0.f, 0.f};
        f32x4 cA = xp_cur, cB = z4, cC = z4, cD = z4;
        cA = __builtin_amdgcn_mfma_f32_16x16x32_bf16(whh_h[0], hf0, cA, 0, 0, 0);
        cC = __builtin_amdgcn_mfma_f32_16x16x32_bf16(whh_l[0], hf0, cC, 0, 0, 0);
        cB = __builtin_amdgcn_mfma_f32_16x16x32_bf16(whh_h[2], hf2, cB, 0, 0, 0);
        cD = __builtin_amdgcn_mfma_f32_16x16x32_bf16(whh_l[2], hf2, cD, 0, 0, 0);
        cA = __builtin_amdgcn_mfma_f32_16x16x32_bf16(whh_h[1], hf1, cA, 0, 0, 0);
        cC = __builtin_amdgcn_mfma_f32_16x16x32_bf16(whh_l[1], hf1, cC, 0, 0, 0);
        cB = __builtin_amdgcn_mfma_f32_16x16x32_bf16(whh_h[3], hf3, cB, 0, 0, 0);
        cD = __builtin_amdgcn_mfma_f32_16x16x32_bf16(whh_l[3], hf3, cD, 0, 0, 0);
        f32x4 acc = (cA + cB) + (cC + cD);

        float t0 = tanh_fast(acc[0]);
        float t1 = tanh_fast(acc[1]);
        float t2 = tanh_fast(acc[2]);
        float t3 = tanh_fast(acc[3]);

        if (t == S_LEN - 1) {
            f32x4 o = {t0, t1, t2, t3};
            *(f32x4*)(out + ((size_t)bb0 + col) * NHID + 16 * w + 4 * kg) = o;
        } else {
            uint2 hb;
            hb.x = cvt_pk(t0, t1);
            hb.y = cvt_pk(t2, t3);
            *(uint2*)(lbase + (((t + 1) & 1) << 12) + wr_off) = hb;  // ds_write_b64
        }
        lds_barrier();
    };

    // ---- prologue
    f32x4 r00, r01, r02, r03, r10, r11, r12, r13;
    bf16x8 P00, P01, P10, P11;
    f32x4 xp_a, xp_b;
    {
        f32x4 v0, v1, v2, v3;
        loadStage(v0, v1, v2, v3, 0);           // x(0) -> xp(0)
        bf16x8 q0, q1;
        packP(q0, q1, v0, v1, v2, v3);
        xp_a = biasv;
        xp_a = __builtin_amdgcn_mfma_f32_16x16x32_bf16(wih_h[0], q0, xp_a, 0, 0, 0);
        xp_a = __builtin_amdgcn_mfma_f32_16x16x32_bf16(wih_h[1], q1, xp_a, 0, 0, 0);
        loadStage(v0, v1, v2, v3, 1);           // x(1) -> P0 slot
        packP(P00, P01, v0, v1, v2, v3);
        loadStage(v0, v1, v2, v3, 2);           // x(2) -> P1 slot
        packP(P10, P11, v0, v1, v2, v3);
    }
    loadStage(r00, r01, r02, r03, 3);           // R0: x(3)
    loadStage(r10, r11, r12, r13, 4);           // R1: x(4)
    __syncthreads();   // one-time: covers hbuf zero-init

    for (int t = 0; t < S_LEN; t += 2) {
        step(t,     r00, r01, r02, r03, P00, P01, xp_a, xp_b);
        step(t + 1, r10, r11, r12, r13, P10, P11, xp_b, xp_a);
    }
}

extern "C" void kernel_launch(void* const* d_in, const int* in_sizes, int n_in,
                              void* d_out, int out_size, void* d_ws, size_t ws_size,
                              hipStream_t stream) {
    const float* x    = (const float*)d_in[0];
    const float* W_ih = (const float*)d_in[1];
    const float* b_ih = (const float*)d_in[2];
    const float* W_hh = (const float*)d_in[3];
    const float* b_hh = (const float*)d_in[4];
    float* out = (float*)d_out;

    dim3 grid(BATCH / BT);
    dim3 block(512);
    rnn_kernel<<<grid, block, 0, stream>>>(x, W_ih, b_ih, W_hh, b_hh, out);
}